// Round 4
// baseline (43.692 us; speedup 1.0000x reference)
//
#include <hip/hip_runtime.h>
#include <math.h>

#define BSZ 16
#define NP 4096
#define MAXGT 32
#define CIN 512
#define NCLS 4
#define RPB 128                    // rows per block
#define NBLK (BSZ * NP / RPB)      // 512 blocks
#define BPB (NP / RPB)             // 32 blocks per batch
#define GRP 4                      // 8-row groups per wave (32 rows/wave)

// ---------------------------------------------------------------------------
// Main kernel: 4 waves/block, 128 rows/block (32 per wave, in 8-row groups).
// Lane l owns columns [8l, 8l+8) of every row: v loads are perfectly
// coalesced (64 lanes x consecutive 32B = 2KB/instruction-pair); weight
// fragments live in 16 float4 VGPRs per lane (loaded once). Per 8-row group
// each lane computes 64 partials, then a 6-stage shfl_xor butterfly reduces
// across lanes, landing sum(r,c) in lane r*8+c. Results go to padded LDS;
// the epilogue (CE, IoU, smooth-L1) runs thread-per-row after one barrier.
// ---------------------------------------------------------------------------
__global__ __launch_bounds__(256, 2) void oicr_main(
    const float* __restrict__ v,
    const float* __restrict__ gt_boxes,
    const int*   __restrict__ gt_counts,
    const float* __restrict__ rois,
    const float* __restrict__ labels,
    const float* __restrict__ pre_score,
    const float* __restrict__ cls_w,
    const float* __restrict__ cls_b,
    const float* __restrict__ reg_w,
    const float* __restrict__ reg_b,
    float* __restrict__ partials)
{
    __shared__ float outb[RPB][9];        // 4.6 KB, pad 9 -> conflict-free
    __shared__ float4 red[256];           // 4 KB reduce scratch
    __shared__ float s_bias[8];
    __shared__ float g_x0[MAXGT], g_y0[MAXGT], g_x1[MAXGT], g_y1[MAXGT];
    __shared__ float g_area[MAXGT];
    __shared__ int   g_valid[MAXGT];
    __shared__ int   s_label;

    const int tid  = threadIdx.x;
    const int lane = tid & 63;
    const int wv   = tid >> 6;                    // wave 0..3
    const int blk  = blockIdx.x;
    const int b    = blk >> 5;                    // 32 blocks per batch
    const int rowblk = blk * RPB;                 // block's first global row
    const int wrow   = rowblk + wv * 32;          // wave's first global row

    // --- tiny per-batch metadata (consumed after the barrier) ---
    if (tid < 8) s_bias[tid] = (tid < 4) ? cls_b[tid] : reg_b[tid - 4];
    if (tid < MAXGT) {
        int cnt = gt_counts[b];
        const float* g = gt_boxes + (size_t)(b * MAXGT + tid) * 4;
        float x0 = g[0], y0 = g[1], x1 = g[2], y1 = g[3];
        g_x0[tid] = x0; g_y0[tid] = y0; g_x1[tid] = x1; g_y1[tid] = y1;
        g_area[tid] = (x1 - x0) * (y1 - y0);
        g_valid[tid] = (tid < cnt) ? 1 : 0;
    }
    if (tid == 0) {
        const float* L = labels + b * NCLS;
        int bi = 0; float bv = L[0];
        #pragma unroll
        for (int c = 1; c < NCLS; ++c) { if (L[c] > bv) { bv = L[c]; bi = c; } }
        s_label = bi;
    }

    // --- per-lane weight fragments: cols [8*lane, 8*lane+8) of each output ---
    float4 Wl[8][2];
    #pragma unroll
    for (int c = 0; c < 4; ++c) {
        Wl[c][0]     = *(const float4*)&cls_w[c * CIN + lane * 8];
        Wl[c][1]     = *(const float4*)&cls_w[c * CIN + lane * 8 + 4];
        Wl[4 + c][0] = *(const float4*)&reg_w[c * CIN + lane * 8];
        Wl[4 + c][1] = *(const float4*)&reg_w[c * CIN + lane * 8 + 4];
    }

    const float4* vb = (const float4*)v + (size_t)wrow * (CIN / 4) + lane * 2;

    for (int g = 0; g < GRP; ++g) {
        // coalesced loads: 8 rows x 32 B per lane
        float4 A[8][2];
        #pragma unroll
        for (int r = 0; r < 8; ++r) {
            const float4* p = vb + (size_t)(g * 8 + r) * (CIN / 4);
            A[r][0] = p[0];
            A[r][1] = p[1];
        }

        // 64 partials: val[r*8+c] = dot(A[r], W[c]) over this lane's 8 cols
        float val[64];
        #pragma unroll
        for (int r = 0; r < 8; ++r) {
            #pragma unroll
            for (int c = 0; c < 8; ++c) {
                float4 a0 = A[r][0], a1 = A[r][1];
                float4 w0 = Wl[c][0], w1 = Wl[c][1];
                val[r * 8 + c] = a0.x * w0.x + a0.y * w0.y + a0.z * w0.z + a0.w * w0.w
                               + a1.x * w1.x + a1.y * w1.y + a1.z * w1.z + a1.w * w1.w;
            }
        }

        // 6-stage butterfly: after stage s, val[p] holds partial for logical
        // index j=(p<<(s+1))|(lane&((2<<s)-1)), summed over lanes matching in
        // bits > s. Ends with lane l holding the full sum for j = l.
        #pragma unroll
        for (int s = 0; s < 6; ++s) {
            const int n = 64 >> s;
            const int hi = (lane >> s) & 1;
            #pragma unroll
            for (int p = 0; p < n; ++p)
                val[p] += __shfl_xor(val[p], 1 << s, 64);
            #pragma unroll
            for (int p2 = 0; p2 < n / 2; ++p2)
                val[p2] = hi ? val[2 * p2 + 1] : val[2 * p2];
        }

        // lane l holds sum for row (l>>3) of this group, output (l&7)
        outb[wv * 32 + g * 8 + (lane >> 3)][lane & 7] = val[0];
    }
    __syncthreads();

    // --- epilogue: thread t < RPB handles block-row t ---
    float px = 0.f, py = 0.f, pz = 0.f, pw = 0.f;
    if (tid < RPB) {
        const int row = rowblk + tid;

        const float cls0 = outb[tid][0] + s_bias[0];
        const float cls1 = outb[tid][1] + s_bias[1];
        const float cls2 = outb[tid][2] + s_bias[2];
        const float cls3 = outb[tid][3] + s_bias[3];
        const float reg0 = outb[tid][4] + s_bias[4];
        const float reg1 = outb[tid][5] + s_bias[5];
        const float reg2 = outb[tid][6] + s_bias[6];
        const float reg3 = outb[tid][7] + s_bias[7];

        const int lbl = s_label;

        // background CE on raw logits
        float mB = fmaxf(fmaxf(cls0, cls1), fmaxf(cls2, cls3));
        float lseB = mB + logf(expf(cls0 - mB) + expf(cls1 - mB) +
                               expf(cls2 - mB) + expf(cls3 - mB));
        float clsL = (lbl == 0) ? cls0 : (lbl == 1) ? cls1 : (lbl == 2) ? cls2 : cls3;
        float ce_bg = lseB - clsL;

        // foreground CE on clipped logits
        const float lo = 1e-7f, hi2 = 1.f - 1e-7f;
        float cc0 = fminf(fmaxf(cls0, lo), hi2);
        float cc1 = fminf(fmaxf(cls1, lo), hi2);
        float cc2 = fminf(fmaxf(cls2, lo), hi2);
        float cc3 = fminf(fmaxf(cls3, lo), hi2);
        float mF = fmaxf(fmaxf(cc0, cc1), fmaxf(cc2, cc3));
        float lseF = mF + logf(expf(cc0 - mF) + expf(cc1 - mF) +
                               expf(cc2 - mF) + expf(cc3 - mF));
        float ccL = (lbl == 0) ? cc0 : (lbl == 1) ? cc1 : (lbl == 2) ? cc2 : cc3;
        float ce_fg = lseF - ccL;
        float ps = pre_score[(size_t)row * NCLS + lbl];

        // IoU over 32 GTs: mask + first-occurrence argmax
        float4 r = *(const float4*)(rois + (size_t)row * 4);
        float rarea = (r.z - r.x) * (r.w - r.y);
        float best = -3.0e38f;
        int   bi = 0;
        int   mk = 0;
        #pragma unroll
        for (int g = 0; g < MAXGT; ++g) {
            float ix0 = fmaxf(r.x, g_x0[g]);
            float iy0 = fmaxf(r.y, g_y0[g]);
            float ix1 = fminf(r.z, g_x1[g]);
            float iy1 = fminf(r.w, g_y1[g]);
            float iw = fmaxf(ix1 - ix0, 0.f);
            float ih = fmaxf(iy1 - iy0, 0.f);
            float inter = iw * ih;
            float iou = inter / (g_area[g] + rarea - inter);
            iou = g_valid[g] ? iou : -1.0f;
            if (iou > best) { best = iou; bi = g; }   // strict > => first max
            mk |= (iou > 0.5f) ? 1 : 0;
        }
        float maskf = mk ? 1.f : 0.f;

        // bbox targets + smooth L1
        float gx0 = g_x0[bi], gy0 = g_y0[bi], gx1 = g_x1[bi], gy1 = g_y1[bi];
        float gx = (gx1 + gx0) * 0.5f, gy = (gy1 + gy0) * 0.5f;
        float gw = (gx1 - gx0) * 0.5f, gh = (gy1 - gy0) * 0.5f;
        float rx = (r.z + r.x) * 0.5f, ry = (r.w + r.y) * 0.5f;
        float rw = (r.z - r.x) * 0.5f, rh = (r.w - r.y) * 0.5f;
        float tx = (gx - rx) / (rw + 1e-8f);
        float ty = (gy - ry) / (rh + 1e-8f);
        float tw = logf(gw / (rw + 1e-8f));
        float th = logf(gh / (rh + 1e-8f));

        float d0 = reg0 - tx, d1 = reg1 - ty, d2 = reg2 - tw, d3 = reg3 - th;
        float a0 = fabsf(d0), a1 = fabsf(d1), a2 = fabsf(d2), a3 = fabsf(d3);
        float s0 = (a0 < 1.f) ? 0.5f * a0 * a0 : a0 - 0.5f;
        float s1 = (a1 < 1.f) ? 0.5f * a1 * a1 : a1 - 0.5f;
        float s2 = (a2 < 1.f) ? 0.5f * a2 * a2 : a2 - 0.5f;
        float s3 = (a3 < 1.f) ? 0.5f * a3 * a3 : a3 - 0.5f;
        float sl1 = s0 + s1 + s2 + s3;

        px = ce_bg;
        py = ce_fg * ps * maskf;
        pz = maskf;
        pw = sl1 * maskf * ps;
    }

    // --- deterministic block tree-reduce over 256 slots ---
    red[tid] = make_float4(px, py, pz, pw);
    __syncthreads();
    #pragma unroll
    for (int s = 128; s > 0; s >>= 1) {
        if (tid < s) {
            float4 o = red[tid + s];
            float4 m2 = red[tid];
            m2.x += o.x; m2.y += o.y; m2.z += o.z; m2.w += o.w;
            red[tid] = m2;
        }
        __syncthreads();
    }
    if (tid == 0) {
        float4 t4 = red[0];
        partials[(size_t)blk * 4 + 0] = t4.x;
        partials[(size_t)blk * 4 + 1] = t4.y;
        partials[(size_t)blk * 4 + 2] = t4.z;
        partials[(size_t)blk * 4 + 3] = t4.w;
    }
}

// ---------------------------------------------------------------------------
// Final combine: lanes 0..15 each sum their batch's 32 block-partials in
// fixed order, compute per-batch terms, wave shuffle-reduce, one write.
// ---------------------------------------------------------------------------
__global__ __launch_bounds__(64) void oicr_final(
    const float* __restrict__ partials,
    const int*   __restrict__ gt_counts,
    float* __restrict__ out)
{
    const int lane = threadIdx.x;
    float S0 = 0.f, S1 = 0.f, S2 = 0.f, S3 = 0.f;
    float c_term = 0.f, cbg_term = 0.f, bg_term = 0.f, l1_term = 0.f;
    if (lane < BSZ) {
        for (int blk = 0; blk < BPB; ++blk) {
            const float* q = partials + (size_t)(lane * BPB + blk) * 4;
            S0 += q[0]; S1 += q[1]; S2 += q[2]; S3 += q[3];
        }
        bool has = gt_counts[lane] > 0;
        float c_fg       = S1 / (S2 + 1e-7f);
        float ce_bg_mean = S0 / (float)NP;
        float l1b        = S3 / (float)(BSZ * NP);
        c_term   = has ? c_fg : 0.f;
        cbg_term = has ? 0.f : ce_bg_mean;
        bg_term  = has ? 0.f : (float)NP;
        l1_term  = has ? l1b : 0.f;
    }
    #pragma unroll
    for (int off = 32; off > 0; off >>= 1) {
        c_term   += __shfl_down(c_term, off);
        cbg_term += __shfl_down(cbg_term, off);
        bg_term  += __shfl_down(bg_term, off);
        l1_term  += __shfl_down(l1_term, off);
    }
    if (lane == 0) {
        out[0] = (c_term + cbg_term / (bg_term + 1e-7f)) / ((float)BSZ + 1e-7f)
                 + l1_term;
    }
}

extern "C" void kernel_launch(void* const* d_in, const int* in_sizes, int n_in,
                              void* d_out, int out_size, void* d_ws, size_t ws_size,
                              hipStream_t stream)
{
    const float* v         = (const float*)d_in[0];
    const float* gt_boxes  = (const float*)d_in[1];
    const int*   gt_counts = (const int*)  d_in[2];
    const float* rois      = (const float*)d_in[3];
    const float* labels    = (const float*)d_in[4];
    const float* pre_score = (const float*)d_in[5];
    const float* cls_w     = (const float*)d_in[6];
    const float* cls_b     = (const float*)d_in[7];
    const float* reg_w     = (const float*)d_in[8];
    const float* reg_b     = (const float*)d_in[9];
    float* out      = (float*)d_out;
    float* partials = (float*)d_ws;   // 512 blocks * 4 floats = 8 KB

    oicr_main<<<dim3(NBLK), dim3(256), 0, stream>>>(
        v, gt_boxes, gt_counts, rois, labels, pre_score,
        cls_w, cls_b, reg_w, reg_b, partials);
    oicr_final<<<dim3(1), dim3(64), 0, stream>>>(partials, gt_counts, out);
}